// Round 2
// 199.341 us; speedup vs baseline: 1.0394x; 1.0394x over previous
//
#include <hip/hip_runtime.h>

#define KK 32
#define HH 6
#define OO 31
#define EPS 1e-6f
#define PTS_BLK 256
#define V_DW (KK * 4 * HH * 8)   // 6144 dwords: V[k][oc(4)][h(6)][8]

typedef float f32x16 __attribute__((ext_vector_type(16)));
typedef float f32x4  __attribute__((ext_vector_type(4)));

// Sigma-folded, o-chunked, zero-padded W. 24.6 KB, rebuilt each launch by the
// prep kernel (inputs may be re-poisoned between iterations).
// Layout: V[k][oc][h][o8], o = oc*8 + o8, col o==31 zero-padded.
//   h=0: W0 - (W3+W5)/s2   (absorbs the -1/s2 terms of coeff3/coeff5)
//   h=1: -W1/s2            (x gw*dy)
//   h=2: -W2/s2            (x gw*dx)
//   h=3:  W3/s4            (x gw*dy^2)
//   h=4:  W4/s4            (x gw*dx*dy)
//   h=5:  W5/s4            (x gw*dx^2)
__device__ __align__(256) float V_dev[V_DW];

__global__ void hermite_prep_kernel(const float* __restrict__ W,
                                    const float* __restrict__ sigmas)
{
    int j = blockIdx.x * 256 + threadIdx.x;
    if (j >= V_DW) return;
    int k  = j / 192;
    int r  = j - k * 192;
    int oc = r / 48;
    int r2 = r - oc * 48;
    int h  = r2 >> 3;
    int o  = oc * 8 + (r2 & 7);
    float s  = sigmas[k];
    float s2 = s * s;
    float i2 = 1.0f / (s2 + EPS);
    float i4 = 1.0f / (s2 * s2 + EPS);
    float v = 0.0f;
    if (o < OO) {
        const float* Wk = W + k * (HH * OO);
        float w = Wk[h * OO + o];
        if (h == 0)      v = w - i2 * (Wk[3 * OO + o] + Wk[5 * OO + o]);
        else if (h <= 2) v = -i2 * w;
        else             v = i4 * w;
    }
    V_dev[j] = v;
}

// One (k, 8-output) chunk: 48 wave-uniform V values fetched via SMEM into
// SGPRs (no 64-lane replication -> LDS pipe completely removed from the main
// loop), then 48 FMAs with the SGPR as the one allowed scalar operand.
// Loads + lgkmcnt(0) live in ONE asm so every consumer data-depends on the
// asm outputs (no hoisting hazard); SMEM may return out-of-order so only
// lgkmcnt(0) is safe anyway.
#define CHUNK(PC, OCB)                                                     \
    {                                                                      \
        f32x16 t0, t1, t2;                                                 \
        asm volatile("s_load_dwordx16 %0, %3, 0x0\n\t"                     \
                     "s_load_dwordx16 %1, %3, 0x40\n\t"                    \
                     "s_load_dwordx16 %2, %3, 0x80\n\t"                    \
                     "s_waitcnt lgkmcnt(0)"                                \
                     : "=&s"(t0), "=&s"(t1), "=&s"(t2)                     \
                     : "s"(PC));                                           \
        _Pragma("unroll")                                                  \
        for (int o = 0; o < 8; ++o) {                                      \
            float a = acc[(OCB) + o];                                      \
            a = fmaf(g,  t0[o],     a);                                    \
            a = fmaf(d1, t0[8 + o], a);                                    \
            a = fmaf(d2, t1[o],     a);                                    \
            a = fmaf(d3, t1[8 + o], a);                                    \
            a = fmaf(d4, t2[o],     a);                                    \
            a = fmaf(d5, t2[8 + o], a);                                    \
            acc[(OCB) + o] = a;                                            \
        }                                                                  \
    }

// 8 consecutive k's against one 64B cd sector already staged in c[16].
#define JBLOCK(VS, GOFF)                                                   \
    _Pragma("unroll")                                                      \
    for (int j = 0; j < 8; ++j) {                                          \
        float dx = c[2 * j], dy = c[2 * j + 1];                            \
        float g  = ga[(GOFF) + j];                                         \
        float d1 = g * dy, d2 = g * dx;                                    \
        float d3 = d1 * dy, d4 = d1 * dx, d5 = d2 * dx;                    \
        const float* pk = (VS) + j * 192;                                  \
        CHUNK(pk,        0)                                                \
        CHUNK(pk + 48,   8)                                                \
        CHUNK(pk + 96,  16)                                                \
        CHUNK(pk + 144, 24)                                                \
    }

// M=1, 256 pts/block. LDS = 31.7 KB epilogue transpose only -> 5 blocks/CU;
// ~90 VGPR -> 5 waves/SIMD; occupancy ~20 waves/CU (vs 8 before).
__global__ __launch_bounds__(256, 4) void hermite_fused_kernel(
    const float* __restrict__ mlp,     // [P, OO]
    const float* __restrict__ cd,      // [P, KK, 2]
    const float* __restrict__ gw,      // [P, KK]
    float* __restrict__ out)           // [P, OO]
{
    __shared__ float smem[PTS_BLK * OO];   // 7936 dwords = 31744 B

    const int tid = threadIdx.x;
    const int p   = blockIdx.x * PTS_BLK + tid;
    const float4* __restrict__ cdv = (const float4*)(cd + (size_t)p * (KK * 2));
    const float4* __restrict__ gwv = (const float4*)(gw + (size_t)p * KK);

    float acc[32];
#pragma unroll
    for (int o = 0; o < 32; ++o) acc[o] = 0.0f;

    const float* __restrict__ Vb = V_dev;

    // 2 outer iterations x 16 k. gw staged 16 k at a time (4 float4 = one
    // full 64B sector/lane); cd staged 8 k at a time (4 float4 = one full
    // 64B sector/lane). All register arrays statically indexed.
#pragma unroll 1
    for (int kt2 = 0; kt2 < 2; ++kt2) {
        float ga[16];
#pragma unroll
        for (int i = 0; i < 4; ++i) {
            float4 t = gwv[kt2 * 4 + i];
            ga[4 * i + 0] = t.x; ga[4 * i + 1] = t.y;
            ga[4 * i + 2] = t.z; ga[4 * i + 3] = t.w;
        }

        float c[16];
#pragma unroll
        for (int i = 0; i < 4; ++i) {
            float4 t = cdv[kt2 * 8 + i];
            c[4 * i + 0] = t.x; c[4 * i + 1] = t.y;
            c[4 * i + 2] = t.z; c[4 * i + 3] = t.w;
        }
        const float* Vs0 = Vb + (size_t)kt2 * (16 * 192);
        JBLOCK(Vs0, 0)

#pragma unroll
        for (int i = 0; i < 4; ++i) {
            float4 t = cdv[kt2 * 8 + 4 + i];
            c[4 * i + 0] = t.x; c[4 * i + 1] = t.y;
            c[4 * i + 2] = t.z; c[4 * i + 3] = t.w;
        }
        const float* Vs1 = Vs0 + 8 * 192;
        JBLOCK(Vs1, 8)
    }

    // Epilogue: transpose through LDS for coalesced float4 mlp*mix -> out.
    // Write banks (31*tid + o) mod 32 = (o - tid) mod 32: conflict-free.
#pragma unroll
    for (int o = 0; o < OO; ++o) smem[tid * OO + o] = acc[o];
    __syncthreads();

    {
        const size_t blk_dw = (size_t)blockIdx.x * (PTS_BLK * OO);
        const f32x4* __restrict__ mlpv = (const f32x4*)(mlp + blk_dw);
        f32x4* __restrict__ outv = (f32x4*)(out + blk_dw);
        const f32x4* mixv = (const f32x4*)smem;
#pragma unroll 2
        for (int j = tid; j < (PTS_BLK * OO) / 4; j += 256) {
            f32x4 m = __builtin_nontemporal_load(&mlpv[j]);
            f32x4 x = mixv[j];
            f32x4 r = m * x;
            __builtin_nontemporal_store(r, &outv[j]);
        }
    }
}

extern "C" void kernel_launch(void* const* d_in, const int* in_sizes, int n_in,
                              void* d_out, int out_size, void* d_ws, size_t ws_size,
                              hipStream_t stream)
{
    const float* mlp    = (const float*)d_in[0]; // [B,N,O]
    const float* cd     = (const float*)d_in[1]; // [B,N,K,2]
    const float* sigmas = (const float*)d_in[2]; // [K]
    const float* gw     = (const float*)d_in[3]; // [B,N,K]
    const float* W      = (const float*)d_in[4]; // [K,H,O]
    float* out          = (float*)d_out;

    const int P = in_sizes[3] / KK;              // B*N = 262144

    hermite_prep_kernel<<<(V_DW + 255) / 256, 256, 0, stream>>>(W, sigmas);
    hermite_fused_kernel<<<P / PTS_BLK, 256, 0, stream>>>(mlp, cd, gw, out);
}

// Round 3
// 198.575 us; speedup vs baseline: 1.0434x; 1.0039x over previous
//
#include <hip/hip_runtime.h>

#define KK 32
#define HH 6
#define OO 31
#define EPS 1e-6f
#define PTS_BLK 512              // 256 threads x M=2 points
#define V_DW (KK * 4 * HH * 8)   // 6144 dwords: V[k][oc(4)][h(6)][8]

typedef float f32x16 __attribute__((ext_vector_type(16)));
typedef float f32x4  __attribute__((ext_vector_type(4)));

// Sigma-folded, o-chunked, zero-padded W. 24.6 KB, rebuilt each launch by the
// prep kernel (inputs may be re-poisoned between iterations).
// Layout: V[k][oc][h][o8], o = oc*8 + o8, col o==31 zero-padded.
//   h=0: W0 - (W3+W5)/s2   h=1: -W1/s2 (x g*dy)   h=2: -W2/s2 (x g*dx)
//   h=3: W3/s4 (x g*dy^2)  h=4: W4/s4 (x g*dx*dy) h=5: W5/s4 (x g*dx^2)
__device__ __align__(256) float V_dev[V_DW];

__global__ void hermite_prep_kernel(const float* __restrict__ W,
                                    const float* __restrict__ sigmas)
{
    int j = blockIdx.x * 256 + threadIdx.x;
    if (j >= V_DW) return;
    int k  = j / 192;
    int r  = j - k * 192;
    int oc = r / 48;
    int r2 = r - oc * 48;
    int h  = r2 >> 3;
    int o  = oc * 8 + (r2 & 7);
    float s  = sigmas[k];
    float s2 = s * s;
    float i2 = 1.0f / (s2 + EPS);
    float i4 = 1.0f / (s2 * s2 + EPS);
    float v = 0.0f;
    if (o < OO) {
        const float* Wk = W + k * (HH * OO);
        float w = Wk[h * OO + o];
        if (h == 0)      v = w - i2 * (Wk[3 * OO + o] + Wk[5 * OO + o]);
        else if (h <= 2) v = -i2 * w;
        else             v = i4 * w;
    }
    V_dev[j] = v;
}

// One (k, 8-output) chunk, M=2 points: 48 wave-uniform V dwords -> SGPRs via
// SMEM (no 64-lane replication), then 96 FMAs (48 per point) each taking the
// SGPR as the one allowed scalar operand. 192 cyc of compute per lgkmcnt(0)
// (vs 96 at M=1) -> SMEM L2 latency (~300 cyc) mostly covered by 2 waves/SIMD.
// Loads + wait in ONE asm: consumers data-depend on outputs (no hoist hazard);
// SMEM returns may be OOO so only lgkmcnt(0) is safe (no counted prefetch).
#define CHUNK2(PC, OCB)                                                    \
    {                                                                      \
        f32x16 t0, t1, t2;                                                 \
        asm volatile("s_load_dwordx16 %0, %3, 0x0\n\t"                     \
                     "s_load_dwordx16 %1, %3, 0x40\n\t"                    \
                     "s_load_dwordx16 %2, %3, 0x80\n\t"                    \
                     "s_waitcnt lgkmcnt(0)"                                \
                     : "=&s"(t0), "=&s"(t1), "=&s"(t2)                     \
                     : "s"(PC));                                           \
        _Pragma("unroll")                                                  \
        for (int o = 0; o < 8; ++o) {                                      \
            float a = accA[(OCB) + o];                                     \
            a = fmaf(gA_, t0[o],     a);                                   \
            a = fmaf(d1A, t0[8 + o], a);                                   \
            a = fmaf(d2A, t1[o],     a);                                   \
            a = fmaf(d3A, t1[8 + o], a);                                   \
            a = fmaf(d4A, t2[o],     a);                                   \
            a = fmaf(d5A, t2[8 + o], a);                                   \
            accA[(OCB) + o] = a;                                           \
            float b = accB[(OCB) + o];                                     \
            b = fmaf(gB_, t0[o],     b);                                   \
            b = fmaf(d1B, t0[8 + o], b);                                   \
            b = fmaf(d2B, t1[o],     b);                                   \
            b = fmaf(d3B, t1[8 + o], b);                                   \
            b = fmaf(d4B, t2[o],     b);                                   \
            b = fmaf(d5B, t2[8 + o], b);                                   \
            accB[(OCB) + o] = b;                                           \
        }                                                                  \
    }

// 8 consecutive k's against one 64B cd sector per point (cA/cB staged).
#define JBLOCK2(VS, GOFF)                                                  \
    _Pragma("unroll")                                                      \
    for (int j = 0; j < 8; ++j) {                                          \
        float dxA = cA[2 * j], dyA = cA[2 * j + 1];                        \
        float gA_ = gaA[(GOFF) + j];                                       \
        float d1A = gA_ * dyA, d2A = gA_ * dxA;                            \
        float d3A = d1A * dyA, d4A = d1A * dxA, d5A = d2A * dxA;           \
        float dxB = cB[2 * j], dyB = cB[2 * j + 1];                        \
        float gB_ = gaB[(GOFF) + j];                                       \
        float d1B = gB_ * dyB, d2B = gB_ * dxB;                            \
        float d3B = d1B * dyB, d4B = d1B * dxB, d5B = d2B * dxB;           \
        const float* pk = (VS) + j * 192;                                  \
        CHUNK2(pk,        0)                                               \
        CHUNK2(pk + 48,   8)                                               \
        CHUNK2(pk + 96,  16)                                               \
        CHUNK2(pk + 144, 24)                                               \
    }

// M=2, 512 pts/block, 256 threads. ~150 VGPR -> 2 waves/SIMD (grid-capped
// anyway: 512 blocks = 2 blocks/CU). LDS 63.5 KB epilogue tile (2 blocks/CU).
__global__ __launch_bounds__(256, 2) void hermite_fused_kernel(
    const float* __restrict__ mlp,     // [P, OO]
    const float* __restrict__ cd,      // [P, KK, 2]
    const float* __restrict__ gw,      // [P, KK]
    float* __restrict__ out)           // [P, OO]
{
    __shared__ float smem[PTS_BLK * OO];   // 15872 dwords = 63488 B

    const int tid = threadIdx.x;
    const int pA  = blockIdx.x * PTS_BLK + tid;   // point B = pA + 256
    const float4* __restrict__ cdvA = (const float4*)(cd + (size_t)pA * (KK * 2));
    const float4* __restrict__ cdvB = cdvA + (256 * KK * 2) / 4;
    const float4* __restrict__ gwvA = (const float4*)(gw + (size_t)pA * KK);
    const float4* __restrict__ gwvB = gwvA + (256 * KK) / 4;

    float accA[32], accB[32];
#pragma unroll
    for (int o = 0; o < 32; ++o) { accA[o] = 0.0f; accB[o] = 0.0f; }

    const float* __restrict__ Vb = V_dev;

    // 2 outer iterations x 16 k. gw staged 16 k/point (4 float4 = one full
    // 64B sector/lane); cd staged 8 k/point (4 float4 = one full sector).
#pragma unroll 1
    for (int kt2 = 0; kt2 < 2; ++kt2) {
        float gaA[16], gaB[16];
#pragma unroll
        for (int i = 0; i < 4; ++i) {
            float4 t = gwvA[kt2 * 4 + i];
            gaA[4 * i + 0] = t.x; gaA[4 * i + 1] = t.y;
            gaA[4 * i + 2] = t.z; gaA[4 * i + 3] = t.w;
        }
#pragma unroll
        for (int i = 0; i < 4; ++i) {
            float4 t = gwvB[kt2 * 4 + i];
            gaB[4 * i + 0] = t.x; gaB[4 * i + 1] = t.y;
            gaB[4 * i + 2] = t.z; gaB[4 * i + 3] = t.w;
        }

        float cA[16], cB[16];
#pragma unroll
        for (int i = 0; i < 4; ++i) {
            float4 t = cdvA[kt2 * 8 + i];
            cA[4 * i + 0] = t.x; cA[4 * i + 1] = t.y;
            cA[4 * i + 2] = t.z; cA[4 * i + 3] = t.w;
        }
#pragma unroll
        for (int i = 0; i < 4; ++i) {
            float4 t = cdvB[kt2 * 8 + i];
            cB[4 * i + 0] = t.x; cB[4 * i + 1] = t.y;
            cB[4 * i + 2] = t.z; cB[4 * i + 3] = t.w;
        }
        const float* Vs0 = Vb + (size_t)kt2 * (16 * 192);
        JBLOCK2(Vs0, 0)

#pragma unroll
        for (int i = 0; i < 4; ++i) {
            float4 t = cdvA[kt2 * 8 + 4 + i];
            cA[4 * i + 0] = t.x; cA[4 * i + 1] = t.y;
            cA[4 * i + 2] = t.z; cA[4 * i + 3] = t.w;
        }
#pragma unroll
        for (int i = 0; i < 4; ++i) {
            float4 t = cdvB[kt2 * 8 + 4 + i];
            cB[4 * i + 0] = t.x; cB[4 * i + 1] = t.y;
            cB[4 * i + 2] = t.z; cB[4 * i + 3] = t.w;
        }
        const float* Vs1 = Vs0 + 8 * 192;
        JBLOCK2(Vs1, 8)
    }

    // Epilogue: transpose through LDS for coalesced float4 mlp*mix -> out.
    // Write banks (31*tid + o) mod 32 = (o - tid) mod 32: conflict-free.
#pragma unroll
    for (int o = 0; o < OO; ++o) {
        smem[tid * OO + o] = accA[o];
        smem[(tid + 256) * OO + o] = accB[o];
    }
    __syncthreads();

    {
        const size_t blk_dw = (size_t)blockIdx.x * (PTS_BLK * OO);
        const f32x4* __restrict__ mlpv = (const f32x4*)(mlp + blk_dw);
        f32x4* __restrict__ outv = (f32x4*)(out + blk_dw);
        const f32x4* mixv = (const f32x4*)smem;
#pragma unroll 2
        for (int j = tid; j < (PTS_BLK * OO) / 4; j += 256) {
            f32x4 m = __builtin_nontemporal_load(&mlpv[j]);
            f32x4 x = mixv[j];
            f32x4 r = m * x;
            __builtin_nontemporal_store(r, &outv[j]);
        }
    }
}

extern "C" void kernel_launch(void* const* d_in, const int* in_sizes, int n_in,
                              void* d_out, int out_size, void* d_ws, size_t ws_size,
                              hipStream_t stream)
{
    const float* mlp    = (const float*)d_in[0]; // [B,N,O]
    const float* cd     = (const float*)d_in[1]; // [B,N,K,2]
    const float* sigmas = (const float*)d_in[2]; // [K]
    const float* gw     = (const float*)d_in[3]; // [B,N,K]
    const float* W      = (const float*)d_in[4]; // [K,H,O]
    float* out          = (float*)d_out;

    const int P = in_sizes[3] / KK;              // B*N = 262144

    hermite_prep_kernel<<<(V_DW + 255) / 256, 256, 0, stream>>>(W, sigmas);
    hermite_fused_kernel<<<P / PTS_BLK, 256, 0, stream>>>(mlp, cd, gw, out);
}